// Round 1
// baseline (1420.246 us; speedup 1.0000x reference)
//
#include <hip/hip_runtime.h>
#include <stdint.h>

#define E_N 200000
#define A_N 1000000

typedef short s16x8 __attribute__((ext_vector_type(8)));
typedef short s16x4 __attribute__((ext_vector_type(4)));
typedef float f32x4 __attribute__((ext_vector_type(4)));

__device__ __forceinline__ ushort f2bf(float f) {
  uint32_t x = __float_as_uint(f);
  uint32_t r = x + 0x7FFFu + ((x >> 16) & 1u);
  return (ushort)(r >> 16);
}

__device__ __forceinline__ float silu_f(float v) {
  return v * (1.0f / (1.0f + __expf(-v)));
}

// swizzled element offset within a [rows][128] bf16 tile (XOR bank-swizzle, G4)
__device__ __forceinline__ int swz(int row, int h) {
  return row * 128 + (h ^ ((row & 7) << 3));
}

// ---------------- prep: weights -> bf16, transposed to [out][in], swizzled ----
__global__ __launch_bounds__(256) void k_prep(
    const float* __restrict__ Wbil, const float* __restrict__ Wsrc,
    const float* __restrict__ Wtgt, const float* __restrict__ WresB,
    const float* __restrict__ Wskip, const float* __restrict__ WresA,
    const float* __restrict__ bsrc, const float* __restrict__ btgt,
    const float* __restrict__ bresB, const float* __restrict__ bskip,
    const float* __restrict__ bresA,
    ushort* __restrict__ wg_bil, ushort* __restrict__ wg_lin,
    float* __restrict__ bias_tab) {
  int tid = blockIdx.x * 256 + threadIdx.x;
  if (tid < 8 * 16384) {
    int b = tid >> 14, r = tid & 16383;
    int i = r >> 7, h = r & 127;
    wg_bil[b * 16384 + swz(i, h)] = f2bf(Wbil[(i * 8 + b) * 128 + h]);
    return;
  }
  tid -= 8 * 16384;
  if (tid < 9 * 16384) {
    int s = tid >> 14, r = tid & 16383;
    int c = r >> 7, h = r & 127;
    const float* src;
    switch (s) {
      case 0: src = Wsrc; break;
      case 1: src = Wtgt; break;
      case 2: src = WresB; break;
      case 3: src = WresB + 16384; break;
      case 4: src = Wskip; break;
      case 5: src = WresA; break;
      case 6: src = WresA + 16384; break;
      case 7: src = WresA + 32768; break;
      default: src = WresA + 49152; break;
    }
    wg_lin[s * 16384 + swz(c, h)] = f2bf(src[h * 128 + c]);
    return;
  }
  tid -= 9 * 16384;
  if (tid < 9 * 128) {
    int s = tid >> 7, c = tid & 127;
    const float* src;
    switch (s) {
      case 0: src = bsrc; break;
      case 1: src = btgt; break;
      case 2: src = bresB; break;
      case 3: src = bresB + 128; break;
      case 4: src = bskip; break;
      case 5: src = bresA; break;
      case 6: src = bresA + 128; break;
      case 7: src = bresA + 256; break;
      default: src = bresA + 384; break;
    }
    bias_tab[s * 128 + c] = src[c];
  }
}

// ---------------- K1: a = angle.reshape(A,42) @ W_angle  -> [A,8] f32 --------
__global__ __launch_bounds__(256) void k_angle(const float* __restrict__ ang,
                                               const float* __restrict__ Wang,
                                               float* __restrict__ a_ws) {
  __shared__ float rows[128 * 42];
  __shared__ float wbuf[42 * 8];
  int t = threadIdx.x;
  int tile0 = blockIdx.x * 128;
  int nrows = A_N - tile0; if (nrows > 128) nrows = 128;
  int cnt = nrows * 42;
  for (int k = t; k < cnt; k += 256) rows[k] = ang[tile0 * 42 + k];
  for (int k = t; k < 336; k += 256) wbuf[k] = Wang[k];
  __syncthreads();
  int row = t >> 1, half = t & 1;
  if (row < nrows) {
    float a0 = 0.f, a1 = 0.f, a2 = 0.f, a3 = 0.f;
    const float* rp = &rows[row * 42];
    const float* wp = &wbuf[half * 4];
#pragma unroll
    for (int k = 0; k < 42; k++) {
      float v = rp[k];
      a0 += v * wp[k * 8 + 0]; a1 += v * wp[k * 8 + 1];
      a2 += v * wp[k * 8 + 2]; a3 += v * wp[k * 8 + 3];
    }
    f32x4 o; o.x = a0; o.y = a1; o.z = a2; o.w = a3;
    *(f32x4*)&a_ws[(tile0 + row) * 8 + half * 4] = o;
  }
}

// ---------------- Kd: d = dist @ W_dist  -> [E,128] f32 ----------------------
__global__ __launch_bounds__(256) void k_dist(const float* __restrict__ dist,
                                              const float* __restrict__ Wd,
                                              float* __restrict__ dtab) {
  __shared__ float w[6 * 128];
  int t = threadIdx.x;
  for (int k = t; k < 768; k += 256) w[k] = Wd[k];
  __syncthreads();
  int gid = blockIdx.x * 256 + t;
  int e = gid >> 2, q = gid & 3;
  if (e >= E_N) return;
  float dv[6];
#pragma unroll
  for (int r = 0; r < 6; r++) dv[r] = dist[e * 6 + r];
#pragma unroll
  for (int j = 0; j < 32; j += 4) {
    int c = q * 32 + j;
    f32x4 o;
#pragma unroll
    for (int jj = 0; jj < 4; jj++) {
      float s = 0.f;
#pragma unroll
      for (int r = 0; r < 6; r++) s += dv[r] * w[r * 128 + c + jj];
      o[jj] = s;
    }
    *(f32x4*)&dtab[e * 128 + c] = o;
  }
}

// ---------------- K2: srcm = message @ W_src + b_src (bf16 MFMA) -------------
__global__ __launch_bounds__(512) void k_srcm(const float* __restrict__ msg,
                                              const ushort* __restrict__ wg_lin,
                                              const float* __restrict__ bias_tab,
                                              float* __restrict__ srcm) {
  __shared__ ushort xb[128 * 128];
  __shared__ ushort wb[16384];
  __shared__ float bias[128];
  int t = threadIdx.x;
  int tile0 = blockIdx.x * 128;
  const f32x4 Z4 = {0.f, 0.f, 0.f, 0.f};
  for (int off = t * 8; off < 16384; off += 4096)
    *(s16x8*)&wb[off] = *(const s16x8*)&wg_lin[off];
  if (t < 128) bias[t] = bias_tab[t];
  {
    int row = t >> 2, l = t & 3;
    int grow = tile0 + row;
#pragma unroll
    for (int j = 0; j < 8; j++) {
      int h = l * 32 + j * 4;
      s16x4 o; o[0] = 0; o[1] = 0; o[2] = 0; o[3] = 0;
      if (grow < E_N) {
        f32x4 v = *(const f32x4*)&msg[grow * 128 + h];
        o[0] = (short)f2bf(v.x); o[1] = (short)f2bf(v.y);
        o[2] = (short)f2bf(v.z); o[3] = (short)f2bf(v.w);
      }
      *(s16x4*)&xb[swz(row, h)] = o;
    }
  }
  __syncthreads();
  int w = t >> 6, lane = t & 63;
  int rbase = w * 16;
  int arow = rbase + (lane & 15);
  int k0 = (lane >> 4) * 8;
  int r0 = (lane >> 4) * 4;
  f32x4 acc[8];
#pragma unroll
  for (int k = 0; k < 4; k++) {
    s16x8 af = *(const s16x8*)&xb[swz(arow, k * 32 + k0)];
#pragma unroll
    for (int nt = 0; nt < 8; nt++) {
      s16x8 bf = *(const s16x8*)&wb[swz(nt * 16 + (lane & 15), k * 32 + k0)];
      acc[nt] = __builtin_amdgcn_mfma_f32_16x16x32_bf16(af, bf, k == 0 ? Z4 : acc[nt], 0, 0, 0);
    }
  }
#pragma unroll
  for (int nt = 0; nt < 8; nt++) {
    int col = nt * 16 + (lane & 15);
    float bv = bias[col];
#pragma unroll
    for (int r = 0; r < 4; r++) {
      int grow = tile0 + rbase + r0 + r;
      if (grow < E_N) srcm[grow * 128 + col] = acc[nt][r] + bv;
    }
  }
}

// ---------------- K3: fused gather + bilinear MFMA + atomic scatter ----------
__global__ __launch_bounds__(512) void k_bil(const int* __restrict__ aidx,
                                             const float* __restrict__ srcm,
                                             const float* __restrict__ dtab,
                                             const float* __restrict__ a_ws,
                                             const ushort* __restrict__ wg_bil,
                                             float* __restrict__ agg) {
  __shared__ ushort smb[256 * 128];   // 64 KB
  __shared__ ushort wb[2][16384];     // 64 KB
  __shared__ float atile[256 * 8];    // 8 KB
  __shared__ int tgt_l[256];
  int t = threadIdx.x;
  int tile0 = blockIdx.x * 256;
  int nrows = A_N - tile0; if (nrows > 256) nrows = 256;
  const f32x4 Z4 = {0.f, 0.f, 0.f, 0.f};

  for (int off = t * 8; off < 16384; off += 4096)
    *(s16x8*)&wb[0][off] = *(const s16x8*)&wg_bil[off];

  if (t < 256) {
    int j = t;
    if (j < nrows) {
      tgt_l[j] = aidx[A_N + tile0 + j];
      *(f32x4*)&atile[j * 8]     = *(const f32x4*)&a_ws[(tile0 + j) * 8];
      *(f32x4*)&atile[j * 8 + 4] = *(const f32x4*)&a_ws[(tile0 + j) * 8 + 4];
    } else {
      tgt_l[j] = 0;
      f32x4 z = Z4;
      *(f32x4*)&atile[j * 8] = z;
      *(f32x4*)&atile[j * 8 + 4] = z;
    }
  }
  {
    int l = t & 31, jj = t >> 5;  // 32 lanes per angle row, jj in 0..15
    int h = l * 4;
#pragma unroll 1
    for (int p = 0; p < 16; p++) {
      int j = p * 16 + jj;
      s16x4 o; o[0] = 0; o[1] = 0; o[2] = 0; o[3] = 0;
      if (j < nrows) {
        int se = aidx[tile0 + j];
        int te = aidx[A_N + tile0 + j];
        f32x4 sv = *(const f32x4*)&srcm[se * 128 + h];
        f32x4 dv = *(const f32x4*)&dtab[te * 128 + h];
        o[0] = (short)f2bf(sv.x * dv.x); o[1] = (short)f2bf(sv.y * dv.y);
        o[2] = (short)f2bf(sv.z * dv.z); o[3] = (short)f2bf(sv.w * dv.w);
      }
      *(s16x4*)&smb[swz(j, h)] = o;
    }
  }
  __syncthreads();

  int w = t >> 6, lane = t & 63;
  int mb = w * 32;
  int lrow0 = mb + (lane & 15);
  int lrow1 = mb + 16 + (lane & 15);
  int k0 = (lane >> 4) * 8;
  int r0 = (lane >> 4) * 4;
  f32x4 OUT[2][8];
#pragma unroll
  for (int mt = 0; mt < 2; mt++)
#pragma unroll
    for (int nt = 0; nt < 8; nt++) OUT[mt][nt] = Z4;

  int buf = 0;
#pragma unroll 1
  for (int b = 0; b < 8; b++) {
    s16x8 pre[4];
    if (b < 7) {
#pragma unroll
      for (int p = 0; p < 4; p++)
        pre[p] = *(const s16x8*)&wg_bil[(b + 1) * 16384 + p * 4096 + t * 8];
    }
    f32x4 T[2][8];
#pragma unroll
    for (int k = 0; k < 4; k++) {
      s16x8 af0 = *(const s16x8*)&smb[swz(lrow0, k * 32 + k0)];
      s16x8 af1 = *(const s16x8*)&smb[swz(lrow1, k * 32 + k0)];
#pragma unroll
      for (int nt = 0; nt < 8; nt++) {
        s16x8 bf = *(const s16x8*)&wb[buf][swz(nt * 16 + (lane & 15), k * 32 + k0)];
        T[0][nt] = __builtin_amdgcn_mfma_f32_16x16x32_bf16(af0, bf, k == 0 ? Z4 : T[0][nt], 0, 0, 0);
        T[1][nt] = __builtin_amdgcn_mfma_f32_16x16x32_bf16(af1, bf, k == 0 ? Z4 : T[1][nt], 0, 0, 0);
      }
    }
#pragma unroll
    for (int mt = 0; mt < 2; mt++) {
      float av[4];
#pragma unroll
      for (int r = 0; r < 4; r++)
        av[r] = atile[(mb + mt * 16 + r0 + r) * 8 + b];
#pragma unroll
      for (int nt = 0; nt < 8; nt++)
#pragma unroll
        for (int r = 0; r < 4; r++)
          OUT[mt][nt][r] += av[r] * T[mt][nt][r];
    }
    if (b < 7) {
#pragma unroll
      for (int p = 0; p < 4; p++)
        *(s16x8*)&wb[buf ^ 1][p * 4096 + t * 8] = pre[p];
    }
    __syncthreads();
    buf ^= 1;
  }
#pragma unroll
  for (int mt = 0; mt < 2; mt++) {
#pragma unroll
    for (int r = 0; r < 4; r++) {
      int row = mb + mt * 16 + r0 + r;
      int te = tgt_l[row];
#pragma unroll
      for (int nt = 0; nt < 8; nt++) {
        int col = nt * 16 + (lane & 15);
        unsafeAtomicAdd(&agg[te * 128 + col], OUT[mt][nt][r]);
      }
    }
  }
}

// ---------------- K4: fused post-chain (8 layers, bf16 MFMA, f32 spine) ------
__global__ __launch_bounds__(512) void k_post(const float* __restrict__ msg,
                                              const ushort* __restrict__ wg_lin,
                                              const float* __restrict__ bias_tab,
                                              float* __restrict__ xout) {
  __shared__ ushort xb[128 * 128];
  __shared__ ushort hb[128 * 128];
  __shared__ ushort wb[2][16384];
  __shared__ float bias[8 * 128];
  int t = threadIdx.x;
  int tile0 = blockIdx.x * 128;
  const f32x4 Z4 = {0.f, 0.f, 0.f, 0.f};

  for (int off = t * 8; off < 16384; off += 4096)
    *(s16x8*)&wb[0][off] = *(const s16x8*)&wg_lin[16384 + off];
  if (t < 128) {
#pragma unroll
    for (int s = 0; s < 8; s++) bias[s * 128 + t] = bias_tab[(s + 1) * 128 + t];
  }
  {
    int row = t >> 2, l = t & 3;
    int grow = tile0 + row;
#pragma unroll
    for (int j = 0; j < 8; j++) {
      int h = l * 32 + j * 4;
      s16x4 o; o[0] = 0; o[1] = 0; o[2] = 0; o[3] = 0;
      if (grow < E_N) {
        f32x4 v = *(const f32x4*)&msg[grow * 128 + h];
        o[0] = (short)f2bf(v.x); o[1] = (short)f2bf(v.y);
        o[2] = (short)f2bf(v.z); o[3] = (short)f2bf(v.w);
      }
      *(s16x4*)&hb[swz(row, h)] = o;
    }
  }
  __syncthreads();

  int w = t >> 6, lane = t & 63;
  int rbase = w * 16;
  int arow = rbase + (lane & 15);
  int k0 = (lane >> 4) * 8;
  int r0 = (lane >> 4) * 4;
  float xreg[8][4];
  int buf = 0;
#pragma unroll 1
  for (int l = 0; l < 8; l++) {
    s16x8 pre[4];
    if (l < 7) {
#pragma unroll
      for (int p = 0; p < 4; p++)
        pre[p] = *(const s16x8*)&wg_lin[(l + 2) * 16384 + p * 4096 + t * 8];
    }
    const ushort* in = (l == 0 || l == 2 || l == 5 || l == 7) ? hb : xb;
    f32x4 acc[8];
#pragma unroll
    for (int k = 0; k < 4; k++) {
      s16x8 af = *(const s16x8*)&in[swz(arow, k * 32 + k0)];
#pragma unroll
      for (int nt = 0; nt < 8; nt++) {
        s16x8 bf = *(const s16x8*)&wb[buf][swz(nt * 16 + (lane & 15), k * 32 + k0)];
        acc[nt] = __builtin_amdgcn_mfma_f32_16x16x32_bf16(af, bf, k == 0 ? Z4 : acc[nt], 0, 0, 0);
      }
    }
    if (l < 7) {
#pragma unroll
      for (int p = 0; p < 4; p++)
        *(s16x8*)&wb[buf ^ 1][p * 4096 + t * 8] = pre[p];
    }
#pragma unroll
    for (int nt = 0; nt < 8; nt++) {
      int col = nt * 16 + (lane & 15);
      float bv = bias[l * 128 + col];
#pragma unroll
      for (int r = 0; r < 4; r++) {
        int row = rbase + r0 + r;
        int grow = tile0 + row;
        float val = acc[nt][r] + bv;
        float nx;
        bool to_x = true;
        if (l == 0) {
          float ag = (grow < E_N) ? xout[grow * 128 + col] : 0.f;
          nx = val + ag;
          xreg[nt][r] = nx;
        } else if (l == 1 || l == 4 || l == 6) {
          nx = silu_f(val);
          to_x = false;
        } else if (l == 3) {
          float m0 = (grow < E_N) ? msg[grow * 128 + col] : 0.f;
          nx = silu_f(val) + m0;
          xreg[nt][r] = nx;
        } else {  // l == 2, 5, 7
          nx = xreg[nt][r] + silu_f(val);
          xreg[nt][r] = nx;
        }
        if (l == 7) {
          if (grow < E_N) xout[grow * 128 + col] = nx;
        } else {
          ushort hv = f2bf(nx);
          if (to_x) xb[swz(row, col)] = hv;
          else hb[swz(row, col)] = hv;
        }
      }
    }
    __syncthreads();
    buf ^= 1;
  }
}

extern "C" void kernel_launch(void* const* d_in, const int* in_sizes, int n_in,
                              void* d_out, int out_size, void* d_ws, size_t ws_size,
                              hipStream_t stream) {
  const float* dist  = (const float*)d_in[0];
  const float* ang   = (const float*)d_in[1];
  const float* msg   = (const float*)d_in[2];
  const int*   aidx  = (const int*)d_in[3];
  const float* Wd    = (const float*)d_in[4];
  const float* Wang  = (const float*)d_in[5];
  const float* Wsrc  = (const float*)d_in[6];
  const float* bsrc  = (const float*)d_in[7];
  const float* Wtgt  = (const float*)d_in[8];
  const float* btgt  = (const float*)d_in[9];
  const float* Wbil  = (const float*)d_in[10];
  const float* WresB = (const float*)d_in[11];
  const float* bresB = (const float*)d_in[12];
  const float* Wskip = (const float*)d_in[13];
  const float* bskip = (const float*)d_in[14];
  const float* WresA = (const float*)d_in[15];
  const float* bresA = (const float*)d_in[16];

  char* ws = (char*)d_ws;
  float*  srcm     = (float*)(ws + 0);
  float*  dtab     = (float*)(ws + 102400000LL);
  float*  a_ws     = (float*)(ws + 204800000LL);
  ushort* wg_bil   = (ushort*)(ws + 236800000LL);
  ushort* wg_lin   = (ushort*)(ws + 237062144LL);
  float*  bias_tab = (float*)(ws + 237357056LL);
  float*  agg      = (float*)d_out;

  (void)in_sizes; (void)n_in; (void)out_size; (void)ws_size;

  hipMemsetAsync(d_out, 0, (size_t)E_N * 128 * 4, stream);
  k_prep<<<1093, 256, 0, stream>>>(Wbil, Wsrc, Wtgt, WresB, Wskip, WresA,
                                   bsrc, btgt, bresB, bskip, bresA,
                                   wg_bil, wg_lin, bias_tab);
  k_angle<<<7813, 256, 0, stream>>>(ang, Wang, a_ws);
  k_dist<<<3125, 256, 0, stream>>>(dist, Wd, dtab);
  k_srcm<<<1563, 512, 0, stream>>>(msg, wg_lin, bias_tab, srcm);
  k_bil<<<3907, 512, 0, stream>>>(aidx, srcm, dtab, a_ws, wg_bil, agg);
  k_post<<<1563, 512, 0, stream>>>(msg, wg_lin, bias_tab, agg);
}

// Round 2
// 1068.094 us; speedup vs baseline: 1.3297x; 1.3297x over previous
//
#include <hip/hip_runtime.h>
#include <stdint.h>

#define E_N 200000
#define A_N 1000000

typedef short s16x8 __attribute__((ext_vector_type(8)));
typedef short s16x4 __attribute__((ext_vector_type(4)));
typedef float f32x4 __attribute__((ext_vector_type(4)));
typedef uint32_t u32x4 __attribute__((ext_vector_type(4)));

__device__ __forceinline__ ushort f2bf(float f) {
  uint32_t x = __float_as_uint(f);
  uint32_t r = x + 0x7FFFu + ((x >> 16) & 1u);
  return (ushort)(r >> 16);
}

__device__ __forceinline__ float bf2f(ushort u) {
  return __uint_as_float(((uint32_t)u) << 16);
}

__device__ __forceinline__ uint32_t cvtpk(float lo, float hi) {
  uint32_t r;
  asm("v_cvt_pk_bf16_f32 %0, %1, %2" : "=v"(r) : "v"(lo), "v"(hi));
  return r;
}

__device__ __forceinline__ float silu_f(float v) {
  return v * (1.0f / (1.0f + __expf(-v)));
}

// swizzled element offset within a [rows][128] bf16 tile (XOR bank-swizzle, G4)
__device__ __forceinline__ int swz(int row, int h) {
  return row * 128 + (h ^ ((row & 7) << 3));
}

// ---------------- prep: weights -> bf16, transposed to [out][in], swizzled ----
__global__ __launch_bounds__(256) void k_prep(
    const float* __restrict__ Wbil, const float* __restrict__ Wsrc,
    const float* __restrict__ Wtgt, const float* __restrict__ WresB,
    const float* __restrict__ Wskip, const float* __restrict__ WresA,
    const float* __restrict__ bsrc, const float* __restrict__ btgt,
    const float* __restrict__ bresB, const float* __restrict__ bskip,
    const float* __restrict__ bresA,
    ushort* __restrict__ wg_bil, ushort* __restrict__ wg_lin,
    float* __restrict__ bias_tab) {
  int tid = blockIdx.x * 256 + threadIdx.x;
  if (tid < 8 * 16384) {
    int b = tid >> 14, r = tid & 16383;
    int i = r >> 7, h = r & 127;
    wg_bil[b * 16384 + swz(i, h)] = f2bf(Wbil[(i * 8 + b) * 128 + h]);
    return;
  }
  tid -= 8 * 16384;
  if (tid < 9 * 16384) {
    int s = tid >> 14, r = tid & 16383;
    int c = r >> 7, h = r & 127;
    const float* src;
    switch (s) {
      case 0: src = Wsrc; break;
      case 1: src = Wtgt; break;
      case 2: src = WresB; break;
      case 3: src = WresB + 16384; break;
      case 4: src = Wskip; break;
      case 5: src = WresA; break;
      case 6: src = WresA + 16384; break;
      case 7: src = WresA + 32768; break;
      default: src = WresA + 49152; break;
    }
    wg_lin[s * 16384 + swz(c, h)] = f2bf(src[h * 128 + c]);
    return;
  }
  tid -= 9 * 16384;
  if (tid < 9 * 128) {
    int s = tid >> 7, c = tid & 127;
    const float* src;
    switch (s) {
      case 0: src = bsrc; break;
      case 1: src = btgt; break;
      case 2: src = bresB; break;
      case 3: src = bresB + 128; break;
      case 4: src = bskip; break;
      case 5: src = bresA; break;
      case 6: src = bresA + 128; break;
      case 7: src = bresA + 256; break;
      default: src = bresA + 384; break;
    }
    bias_tab[s * 128 + c] = src[c];
  }
}

// ---------------- K1: a = angle.reshape(A,42) @ W_angle  -> [A,8] f32 --------
__global__ __launch_bounds__(256) void k_angle(const float* __restrict__ ang,
                                               const float* __restrict__ Wang,
                                               float* __restrict__ a_ws) {
  __shared__ float rows[128 * 42];
  __shared__ float wbuf[42 * 8];
  int t = threadIdx.x;
  int tile0 = blockIdx.x * 128;
  int nrows = A_N - tile0; if (nrows > 128) nrows = 128;
  if (nrows == 128) {
    const f32x4* src = (const f32x4*)(ang + (size_t)tile0 * 42);
    f32x4* dst = (f32x4*)rows;
    for (int k = t; k < 1344; k += 256) dst[k] = src[k];
  } else {
    int cnt = nrows * 42;
    for (int k = t; k < cnt; k += 256) rows[k] = ang[(size_t)tile0 * 42 + k];
  }
  for (int k = t; k < 336; k += 256) wbuf[k] = Wang[k];
  __syncthreads();
  int row = t >> 1, half = t & 1;
  if (row < nrows) {
    float a0 = 0.f, a1 = 0.f, a2 = 0.f, a3 = 0.f;
    const float* rp = &rows[row * 42];
    const float* wp = &wbuf[half * 4];
#pragma unroll
    for (int k = 0; k < 42; k++) {
      float v = rp[k];
      a0 += v * wp[k * 8 + 0]; a1 += v * wp[k * 8 + 1];
      a2 += v * wp[k * 8 + 2]; a3 += v * wp[k * 8 + 3];
    }
    f32x4 o; o.x = a0; o.y = a1; o.z = a2; o.w = a3;
    *(f32x4*)&a_ws[(tile0 + row) * 8 + half * 4] = o;
  }
}

// ---------------- Kd: d = dist @ W_dist  -> [E,128] bf16 ---------------------
__global__ __launch_bounds__(256) void k_dist(const float* __restrict__ dist,
                                              const float* __restrict__ Wd,
                                              ushort* __restrict__ dtab) {
  __shared__ float w[6 * 128];
  int t = threadIdx.x;
  for (int k = t; k < 768; k += 256) w[k] = Wd[k];
  __syncthreads();
  int gid = blockIdx.x * 256 + t;
  int e = gid >> 2, q = gid & 3;
  if (e >= E_N) return;
  float dv[6];
#pragma unroll
  for (int r = 0; r < 6; r++) dv[r] = dist[e * 6 + r];
#pragma unroll
  for (int j = 0; j < 32; j += 4) {
    int c = q * 32 + j;
    s16x4 o;
#pragma unroll
    for (int jj = 0; jj < 4; jj++) {
      float s = 0.f;
#pragma unroll
      for (int r = 0; r < 6; r++) s += dv[r] * w[r * 128 + c + jj];
      o[jj] = (short)f2bf(s);
    }
    *(s16x4*)&dtab[e * 128 + c] = o;
  }
}

// ---------------- K2: srcm = message @ W_src + b_src (bf16 MFMA) -> bf16 -----
__global__ __launch_bounds__(512) void k_srcm(const float* __restrict__ msg,
                                              const ushort* __restrict__ wg_lin,
                                              const float* __restrict__ bias_tab,
                                              ushort* __restrict__ srcm) {
  __shared__ ushort xb[128 * 128];
  __shared__ ushort wb[16384];
  __shared__ float bias[128];
  int t = threadIdx.x;
  int tile0 = blockIdx.x * 128;
  const f32x4 Z4 = {0.f, 0.f, 0.f, 0.f};
  for (int off = t * 8; off < 16384; off += 4096)
    *(s16x8*)&wb[off] = *(const s16x8*)&wg_lin[off];
  if (t < 128) bias[t] = bias_tab[t];
  {
    int row = t >> 2, l = t & 3;
    int grow = tile0 + row;
#pragma unroll
    for (int j = 0; j < 8; j++) {
      int h = l * 32 + j * 4;
      s16x4 o; o[0] = 0; o[1] = 0; o[2] = 0; o[3] = 0;
      if (grow < E_N) {
        f32x4 v = *(const f32x4*)&msg[(size_t)grow * 128 + h];
        o[0] = (short)f2bf(v.x); o[1] = (short)f2bf(v.y);
        o[2] = (short)f2bf(v.z); o[3] = (short)f2bf(v.w);
      }
      *(s16x4*)&xb[swz(row, h)] = o;
    }
  }
  __syncthreads();
  int w = t >> 6, lane = t & 63;
  int rbase = w * 16;
  int arow = rbase + (lane & 15);
  int k0 = (lane >> 4) * 8;
  int r0 = (lane >> 4) * 4;
  f32x4 acc[8];
#pragma unroll
  for (int k = 0; k < 4; k++) {
    s16x8 af = *(const s16x8*)&xb[swz(arow, k * 32 + k0)];
#pragma unroll
    for (int nt = 0; nt < 8; nt++) {
      s16x8 bf = *(const s16x8*)&wb[swz(nt * 16 + (lane & 15), k * 32 + k0)];
      acc[nt] = __builtin_amdgcn_mfma_f32_16x16x32_bf16(af, bf, k == 0 ? Z4 : acc[nt], 0, 0, 0);
    }
  }
#pragma unroll
  for (int nt = 0; nt < 8; nt++) {
    int col = nt * 16 + (lane & 15);
    float bv = bias[col];
#pragma unroll
    for (int r = 0; r < 4; r++) {
      int grow = tile0 + rbase + r0 + r;
      if (grow < E_N) srcm[(size_t)grow * 128 + col] = f2bf(acc[nt][r] + bv);
    }
  }
}

// ---------------- K3: fused gather + bilinear MFMA + atomic scatter ----------
// out[a,i] = sum_b sum_h (a[a,b]*sm[a,h]) * Wb[b][i,h]; a_b folded into A frags.
__global__ __launch_bounds__(256) void k_bil(const int* __restrict__ aidx,
                                             const ushort* __restrict__ srcm,
                                             const ushort* __restrict__ dtab,
                                             const float* __restrict__ a_ws,
                                             const ushort* __restrict__ wg_bil,
                                             float* __restrict__ agg) {
  __shared__ ushort wb[2][16384];
  int t = threadIdx.x;
  int lane = t & 63, w = t >> 6;
  int tile0 = blockIdx.x * 128;
  int mb = w * 32;
  int r15 = lane & 15, hi = lane >> 4;
  int k0 = hi * 8;
  int r0 = hi * 4;
  const f32x4 Z4 = {0.f, 0.f, 0.f, 0.f};

  // stage b=0 into wb[0] (arrays pre-swizzled -> linear copy)
  {
    const ushort* gs = wg_bil + w * 4096 + lane * 8;
    ushort* ls = &wb[0][w * 4096];
#pragma unroll
    for (int i = 0; i < 8; i++)
      __builtin_amdgcn_global_load_lds(
          (const __attribute__((address_space(1))) void*)(gs + i * 512),
          (__attribute__((address_space(3))) void*)(ls + i * 512), 16, 0, 0);
  }

  // gather sm = srcm[src]*d[tgt] (f32 regs), a values, output-row targets
  float smv[2][4][8];
  float av[2][8];
  int teo[2][4];
#pragma unroll
  for (int mt = 0; mt < 2; mt++) {
    int grow = tile0 + mb + mt * 16 + r15;
    int ok = (grow < A_N);
    int se = ok ? aidx[grow] : 0;
    int te = ok ? aidx[A_N + grow] : 0;
    if (ok) {
      f32x4 a0 = *(const f32x4*)&a_ws[(size_t)grow * 8];
      f32x4 a1 = *(const f32x4*)&a_ws[(size_t)grow * 8 + 4];
#pragma unroll
      for (int j = 0; j < 4; j++) { av[mt][j] = a0[j]; av[mt][4 + j] = a1[j]; }
    } else {
#pragma unroll
      for (int j = 0; j < 8; j++) av[mt][j] = 0.f;
    }
#pragma unroll
    for (int k = 0; k < 4; k++) {
      s16x8 sv = *(const s16x8*)&srcm[(size_t)se * 128 + k * 32 + k0];
      s16x8 dv = *(const s16x8*)&dtab[(size_t)te * 128 + k * 32 + k0];
#pragma unroll
      for (int j = 0; j < 8; j++)
        smv[mt][k][j] = bf2f((ushort)sv[j]) * bf2f((ushort)dv[j]);
    }
#pragma unroll
    for (int r = 0; r < 4; r++) {
      int orow = tile0 + mb + mt * 16 + r0 + r;
      teo[mt][r] = (orow < A_N) ? aidx[A_N + orow] : 0;
    }
  }

  f32x4 OUT[2][8];
#pragma unroll
  for (int mt = 0; mt < 2; mt++)
#pragma unroll
    for (int nt = 0; nt < 8; nt++) OUT[mt][nt] = Z4;

  __syncthreads();  // wb[0] staged (barrier drains vmcnt)

#pragma unroll
  for (int b = 0; b < 8; b++) {
    int buf = b & 1;
    if (b < 7) {  // prefetch next W-slice into other buffer
      const ushort* gs = wg_bil + (b + 1) * 16384 + w * 4096 + lane * 8;
      ushort* ls = &wb[buf ^ 1][w * 4096];
#pragma unroll
      for (int i = 0; i < 8; i++)
        __builtin_amdgcn_global_load_lds(
            (const __attribute__((address_space(1))) void*)(gs + i * 512),
            (__attribute__((address_space(3))) void*)(ls + i * 512), 16, 0, 0);
    }
    float a0b = av[0][b], a1b = av[1][b];
#pragma unroll
    for (int k = 0; k < 4; k++) {
      u32x4 w0, w1;
#pragma unroll
      for (int jj = 0; jj < 4; jj++) {
        w0[jj] = cvtpk(a0b * smv[0][k][2 * jj], a0b * smv[0][k][2 * jj + 1]);
        w1[jj] = cvtpk(a1b * smv[1][k][2 * jj], a1b * smv[1][k][2 * jj + 1]);
      }
      s16x8 af0 = __builtin_bit_cast(s16x8, w0);
      s16x8 af1 = __builtin_bit_cast(s16x8, w1);
#pragma unroll
      for (int nt = 0; nt < 8; nt++) {
        s16x8 bf = *(const s16x8*)&wb[buf][swz(nt * 16 + r15, k * 32 + k0)];
        OUT[0][nt] = __builtin_amdgcn_mfma_f32_16x16x32_bf16(af0, bf, OUT[0][nt], 0, 0, 0);
        OUT[1][nt] = __builtin_amdgcn_mfma_f32_16x16x32_bf16(af1, bf, OUT[1][nt], 0, 0, 0);
      }
    }
    __syncthreads();  // prefetch landed + all reads of wb[buf] done
  }

#pragma unroll
  for (int mt = 0; mt < 2; mt++) {
#pragma unroll
    for (int r = 0; r < 4; r++) {
      float* base = &agg[(size_t)teo[mt][r] * 128];
#pragma unroll
      for (int nt = 0; nt < 8; nt++)
        unsafeAtomicAdd(base + nt * 16 + r15, OUT[mt][nt][r]);
    }
  }
}

// ---------------- K4: fused post-chain (8 layers, bf16 MFMA, f32 spine) ------
__global__ __launch_bounds__(512) void k_post(const float* __restrict__ msg,
                                              const ushort* __restrict__ wg_lin,
                                              const float* __restrict__ bias_tab,
                                              float* __restrict__ xout) {
  __shared__ ushort xb[128 * 128];
  __shared__ ushort hb[128 * 128];
  __shared__ ushort wb[2][16384];
  __shared__ float bias[8 * 128];
  int t = threadIdx.x;
  int tile0 = blockIdx.x * 128;
  const f32x4 Z4 = {0.f, 0.f, 0.f, 0.f};

  for (int off = t * 8; off < 16384; off += 4096)
    *(s16x8*)&wb[0][off] = *(const s16x8*)&wg_lin[16384 + off];
  if (t < 128) {
#pragma unroll
    for (int s = 0; s < 8; s++) bias[s * 128 + t] = bias_tab[(s + 1) * 128 + t];
  }
  {
    int row = t >> 2, l = t & 3;
    int grow = tile0 + row;
#pragma unroll
    for (int j = 0; j < 8; j++) {
      int h = l * 32 + j * 4;
      s16x4 o; o[0] = 0; o[1] = 0; o[2] = 0; o[3] = 0;
      if (grow < E_N) {
        f32x4 v = *(const f32x4*)&msg[(size_t)grow * 128 + h];
        o[0] = (short)f2bf(v.x); o[1] = (short)f2bf(v.y);
        o[2] = (short)f2bf(v.z); o[3] = (short)f2bf(v.w);
      }
      *(s16x4*)&hb[swz(row, h)] = o;
    }
  }
  __syncthreads();

  int w = t >> 6, lane = t & 63;
  int rbase = w * 16;
  int arow = rbase + (lane & 15);
  int k0 = (lane >> 4) * 8;
  int r0 = (lane >> 4) * 4;
  float xreg[8][4];
  int buf = 0;
#pragma unroll 1
  for (int l = 0; l < 8; l++) {
    s16x8 pre[4];
    if (l < 7) {
#pragma unroll
      for (int p = 0; p < 4; p++)
        pre[p] = *(const s16x8*)&wg_lin[(l + 2) * 16384 + p * 4096 + t * 8];
    }
    const ushort* in = (l == 0 || l == 2 || l == 5 || l == 7) ? hb : xb;
    f32x4 acc[8];
#pragma unroll
    for (int k = 0; k < 4; k++) {
      s16x8 af = *(const s16x8*)&in[swz(arow, k * 32 + k0)];
#pragma unroll
      for (int nt = 0; nt < 8; nt++) {
        s16x8 bf = *(const s16x8*)&wb[buf][swz(nt * 16 + (lane & 15), k * 32 + k0)];
        acc[nt] = __builtin_amdgcn_mfma_f32_16x16x32_bf16(af, bf, k == 0 ? Z4 : acc[nt], 0, 0, 0);
      }
    }
    if (l < 7) {
#pragma unroll
      for (int p = 0; p < 4; p++)
        *(s16x8*)&wb[buf ^ 1][p * 4096 + t * 8] = pre[p];
    }
#pragma unroll
    for (int nt = 0; nt < 8; nt++) {
      int col = nt * 16 + (lane & 15);
      float bv = bias[l * 128 + col];
#pragma unroll
      for (int r = 0; r < 4; r++) {
        int row = rbase + r0 + r;
        int grow = tile0 + row;
        float val = acc[nt][r] + bv;
        float nx;
        bool to_x = true;
        if (l == 0) {
          float ag = (grow < E_N) ? xout[(size_t)grow * 128 + col] : 0.f;
          nx = val + ag;
          xreg[nt][r] = nx;
        } else if (l == 1 || l == 4 || l == 6) {
          nx = silu_f(val);
          to_x = false;
        } else if (l == 3) {
          float m0 = (grow < E_N) ? msg[(size_t)grow * 128 + col] : 0.f;
          nx = silu_f(val) + m0;
          xreg[nt][r] = nx;
        } else {  // l == 2, 5, 7
          nx = xreg[nt][r] + silu_f(val);
          xreg[nt][r] = nx;
        }
        if (l == 7) {
          if (grow < E_N) xout[(size_t)grow * 128 + col] = nx;
        } else {
          ushort hv = f2bf(nx);
          if (to_x) xb[swz(row, col)] = hv;
          else hb[swz(row, col)] = hv;
        }
      }
    }
    __syncthreads();
    buf ^= 1;
  }
}

extern "C" void kernel_launch(void* const* d_in, const int* in_sizes, int n_in,
                              void* d_out, int out_size, void* d_ws, size_t ws_size,
                              hipStream_t stream) {
  const float* dist  = (const float*)d_in[0];
  const float* ang   = (const float*)d_in[1];
  const float* msg   = (const float*)d_in[2];
  const int*   aidx  = (const int*)d_in[3];
  const float* Wd    = (const float*)d_in[4];
  const float* Wang  = (const float*)d_in[5];
  const float* Wsrc  = (const float*)d_in[6];
  const float* bsrc  = (const float*)d_in[7];
  const float* Wtgt  = (const float*)d_in[8];
  const float* btgt  = (const float*)d_in[9];
  const float* Wbil  = (const float*)d_in[10];
  const float* WresB = (const float*)d_in[11];
  const float* bresB = (const float*)d_in[12];
  const float* Wskip = (const float*)d_in[13];
  const float* bskip = (const float*)d_in[14];
  const float* WresA = (const float*)d_in[15];
  const float* bresA = (const float*)d_in[16];

  char* ws = (char*)d_ws;
  ushort* srcm_bf  = (ushort*)(ws + 0);
  ushort* dtab_bf  = (ushort*)(ws + 51200000LL);
  float*  a_ws     = (float*)(ws + 102400000LL);
  ushort* wg_bil   = (ushort*)(ws + 134400000LL);
  ushort* wg_lin   = (ushort*)(ws + 134662144LL);
  float*  bias_tab = (float*)(ws + 134957056LL);
  float*  agg      = (float*)d_out;

  (void)in_sizes; (void)n_in; (void)out_size; (void)ws_size;

  hipMemsetAsync(d_out, 0, (size_t)E_N * 128 * 4, stream);
  k_prep<<<1093, 256, 0, stream>>>(Wbil, Wsrc, Wtgt, WresB, Wskip, WresA,
                                   bsrc, btgt, bresB, bskip, bresA,
                                   wg_bil, wg_lin, bias_tab);
  k_angle<<<7813, 256, 0, stream>>>(ang, Wang, a_ws);
  k_dist<<<3125, 256, 0, stream>>>(dist, Wd, dtab_bf);
  k_srcm<<<1563, 512, 0, stream>>>(msg, wg_lin, bias_tab, srcm_bf);
  k_bil<<<7813, 256, 0, stream>>>(aidx, srcm_bf, dtab_bf, a_ws, wg_bil, agg);
  k_post<<<1563, 512, 0, stream>>>(msg, wg_lin, bias_tab, agg);
}